// Round 4
// baseline (575.469 us; speedup 1.0000x reference)
//
#include <hip/hip_runtime.h>

// 2-layer GRU (B=4096, S=512, IN=4, H=32) + FC(32->32) + FC(32->1), fp32 in/out.
// 2 waves/block (one per layer), 16 batch rows/block, 256 blocks.
// LANE-LOCAL recurrence: A-tile row permutation (tile s, D-row 4q+r <-> unit
// 8q+4s+r) makes each lane's MFMA output exactly its own next-step B-fragment
// -> h-recurrence never leaves registers (no LDS/barrier/cross-lane on chain).
// MFMA 16x16x32 bf16 hi/lo split (~fp32 accuracy). Inter-layer h1 handoff via
// small double-buffered LDS (off the recurrence path), 1 barrier/iter.
// x bulk-staged 16 steps ahead in an LDS ring.

#define SEQ 512
#define LOG2E 1.44269504088896340736f

typedef __attribute__((ext_vector_type(8))) short  short8;
typedef __attribute__((ext_vector_type(4))) float  f32x4;
typedef __attribute__((ext_vector_type(4))) unsigned uint4v;

static __device__ __forceinline__ unsigned short f2bf(float f) {
    unsigned u = __builtin_bit_cast(unsigned, f);
    return (unsigned short)((u + 0x7fffu + ((u >> 16) & 1u)) >> 16);
}
static __device__ __forceinline__ float bf2f(unsigned short b) {
    return __builtin_bit_cast(float, ((unsigned)b) << 16);
}
static __device__ __forceinline__ unsigned cvtpk(float a, float b) {
    unsigned r;
    asm("v_cvt_pk_bf16_f32 %0, %1, %2" : "=v"(r) : "v"(a), "v"(b));
    return r;
}
static __device__ __forceinline__ float sigm(float x) {
    return __builtin_amdgcn_rcpf(1.0f + __builtin_amdgcn_exp2f(-LOG2E * x));
}
static __device__ __forceinline__ float tanh_(float x) {
    return 1.0f - 2.0f * __builtin_amdgcn_rcpf(1.0f + __builtin_amdgcn_exp2f((2.0f * LOG2E) * x));
}

#define MFMA(A, B, C) __builtin_amdgcn_mfma_f32_16x16x32_bf16((A), (B), (C), 0, 0, 0)

// Ah*Bh + Al*Bh + Ah*Bl + bias as two parallel chains (depth 2) + add.
static __device__ __forceinline__ f32x4 side3(short8 Ah, short8 Al,
                                              short8 Bh, short8 Bl, f32x4 bias) {
    f32x4 zero = {0.0f, 0.0f, 0.0f, 0.0f};
    f32x4 p = MFMA(Ah, Bh, bias);
    f32x4 s = MFMA(Ah, Bl, zero);
    s = MFMA(Al, Bh, s);
    return p + s;
}

static __device__ __forceinline__ void cvt8(const float* p, short8& h8, short8& l8) {
    f32x4 v0 = *(const f32x4*)p;
    f32x4 v1 = *(const f32x4*)(p + 4);
#pragma unroll
    for (int e = 0; e < 8; ++e) {
        float v = (e < 4) ? v0[e] : v1[e - 4];
        unsigned short hb = f2bf(v);
        h8[e] = (short)hb;
        l8[e] = (short)f2bf(v - bf2f(hb));
    }
}

__global__ __launch_bounds__(128, 1) void gru_fused(
    const float* __restrict__ x,
    const float* __restrict__ Wih0, const float* __restrict__ Whh0,
    const float* __restrict__ bih0, const float* __restrict__ bhh0,
    const float* __restrict__ Wih1, const float* __restrict__ Whh1,
    const float* __restrict__ bih1, const float* __restrict__ bhh1,
    const float* __restrict__ Wfc2, const float* __restrict__ bfc2,
    const float* __restrict__ Wfc,  const float* __restrict__ bfc,
    float* __restrict__ out)
{
    const int tid  = threadIdx.x;
    const int lane = tid & 63;
    const int wv   = tid >> 6;      // 0 = layer0, 1 = layer1
    const int c    = lane & 15;     // batch col
    const int q    = lane >> 4;     // 0..3
    const int b0   = blockIdx.x * 16;

    // LDS: XS x-ring: 32 steps x 16 rows x 16B = 8192 B
    //      H1 handoff: 2 bufs x (hi 1024 + lo 1024) = 4096 B
    __shared__ __align__(16) char smem[8192 + 4096];
    f32x4* XS = (f32x4*)smem;
    char*  H1 = smem + 8192;

    const float* Wu  = wv ? Wih1 : Wih0;   // u-side (x for L0, h1 for L1)
    const float* Wh  = wv ? Whh1 : Whh0;
    const float* bu  = wv ? bih1 : bih0;
    const float* bhp = wv ? bhh1 : bhh0;

    // ---- weight fragments, permuted row mapping ----
    // tile j = 2*G + s (G: 0=r,1=z,2=n gates; s: unit sub-tile)
    // A-frag row c of tile (G,s) = W row [32G + u(c,s)], u(c,s)=8*(c>>2)+4s+(c&3)
    // => D-row 4q+r of tile (G,s) = gate-unit 8q+4s+r  (lane-local recurrence)
    short8 wuh[6], wul[6], whhh[6], whhl[6];
    f32x4  bxv[6], bhv[6];
#pragma unroll
    for (int j = 0; j < 6; ++j) {
        const int G = j >> 1, s = j & 1;
        const int rowA = 32 * G + 8 * (c >> 2) + 4 * s + (c & 3);
        cvt8(Wh + rowA * 32 + 8 * q, whhh[j], whhl[j]);
        if (wv) {
            cvt8(Wu + rowA * 32 + 8 * q, wuh[j], wul[j]);
        } else {
            short8 h8 = {0, 0, 0, 0, 0, 0, 0, 0};
            short8 l8 = {0, 0, 0, 0, 0, 0, 0, 0};
            if (q == 0) {               // Wih0 is 96x4: k<4 only
                f32x4 v = *(const f32x4*)(Wu + rowA * 4);
#pragma unroll
                for (int e = 0; e < 4; ++e) {
                    unsigned short hb = f2bf(v[e]);
                    h8[e] = (short)hb;
                    l8[e] = (short)f2bf(v[e] - bf2f(hb));
                }
            }
            wuh[j] = h8;
            wul[j] = l8;
        }
        bxv[j] = *(const f32x4*)(bu  + 32 * G + 8 * q + 4 * s);
        bhv[j] = *(const f32x4*)(bhp + 32 * G + 8 * q + 4 * s);
    }

    // ---- prologue: stage x steps 0..15 ----
    {
        const int r = tid & 15, s0 = tid >> 4;   // s0: 0..7
#pragma unroll
        for (int k = 0; k < 2; ++k) {
            const int step = s0 + 8 * k;
            XS[step * 16 + r] = *(const f32x4*)(x + ((long)(b0 + r) * SEQ + step) * 4);
        }
    }

    // recurrent state: fp32 master + self-held bf16 hi/lo B-fragment
    uint4v sh  = {0, 0, 0, 0};
    uint4v slo = {0, 0, 0, 0};
    float hst[2][4] = {{0, 0, 0, 0}, {0, 0, 0, 0}};

    __syncthreads();

    // ---- main loop: iter i -> L0 does step i (i<SEQ), L1 does step i-1 ----
#pragma unroll 2
    for (int i = 0; i <= SEQ; ++i) {
        if ((i & 15) == 0) {           // stage 16 steps, 16 iters ahead
            const int base = i + 16;
            const int r = tid & 15, s0 = tid >> 4;
#pragma unroll
            for (int k = 0; k < 2; ++k) {
                const int step = base + s0 + 8 * k;
                if (step < SEQ)
                    XS[(step & 31) * 16 + r] =
                        *(const f32x4*)(x + ((long)(b0 + r) * SEQ + step) * 4);
            }
        }

        const bool act = (wv == 0) ? (i < SEQ) : (i >= 1);
        if (act) {
            // u-side B fragment
            short8 uh, ul;
            if (wv == 0) {
                short8 z8 = {0, 0, 0, 0, 0, 0, 0, 0};
                uh = z8; ul = z8;
                if (q == 0) {
                    f32x4 xv = XS[(i & 31) * 16 + c];
#pragma unroll
                    for (int e = 0; e < 4; ++e) {
                        unsigned short hb = f2bf(xv[e]);
                        uh[e] = (short)hb;
                        ul[e] = (short)f2bf(xv[e] - bf2f(hb));
                    }
                }
            } else {
                const char* src = H1 + ((i + 1) & 1) * 2048;
                uh = *(const short8*)(src + lane * 16);
                ul = *(const short8*)(src + 1024 + lane * 16);
            }

            const short8 shB = __builtin_bit_cast(short8, sh);
            const short8 slB = __builtin_bit_cast(short8, slo);

            f32x4 ax[6], ah[6];
#pragma unroll
            for (int j = 0; j < 6; ++j)
                ax[j] = side3(wuh[j], wul[j], uh, ul, bxv[j]);
#pragma unroll
            for (int j = 0; j < 6; ++j)
                ah[j] = side3(whhh[j], whhl[j], shB, slB, bhv[j]);

            // gates: lane (c,q) owns units 8q+4s+r of batch c
            float hv[2][4];
#pragma unroll
            for (int s = 0; s < 2; ++s)
#pragma unroll
                for (int r = 0; r < 4; ++r) {
                    float rg = sigm(ax[s][r] + ah[s][r]);
                    float zg = sigm(ax[2 + s][r] + ah[2 + s][r]);
                    float ng = tanh_(ax[4 + s][r] + rg * ah[4 + s][r]);
                    float hN = ng + zg * (hst[s][r] - ng);
                    hst[s][r] = hN;
                    hv[s][r] = hN;
                }

            // pack next-step B-frag (lane-local): elem e<4 -> s=0,r=e; e>=4 -> s=1
            unsigned w0 = cvtpk(hv[0][0], hv[0][1]);
            unsigned w1 = cvtpk(hv[0][2], hv[0][3]);
            unsigned w2 = cvtpk(hv[1][0], hv[1][1]);
            unsigned w3 = cvtpk(hv[1][2], hv[1][3]);
            unsigned e0 = cvtpk(hv[0][0] - bf2f((unsigned short)(w0 & 0xffffu)),
                                hv[0][1] - bf2f((unsigned short)(w0 >> 16)));
            unsigned e1 = cvtpk(hv[0][2] - bf2f((unsigned short)(w1 & 0xffffu)),
                                hv[0][3] - bf2f((unsigned short)(w1 >> 16)));
            unsigned e2 = cvtpk(hv[1][0] - bf2f((unsigned short)(w2 & 0xffffu)),
                                hv[1][1] - bf2f((unsigned short)(w2 >> 16)));
            unsigned e3 = cvtpk(hv[1][2] - bf2f((unsigned short)(w3 & 0xffffu)),
                                hv[1][3] - bf2f((unsigned short)(w3 >> 16)));
            uint4v nsh = {w0, w1, w2, w3};
            uint4v nsl = {e0, e1, e2, e3};
            sh = nsh;
            slo = nsl;

            if (wv == 0) {             // publish h1[i] for layer 1 (ready-made frag)
                char* dst = H1 + (i & 1) * 2048;
                *(uint4v*)(dst + lane * 16) = sh;
                *(uint4v*)(dst + 1024 + lane * 16) = slo;
            }
        }
        __syncthreads();
    }

    // ---- epilogue: out[b] = Weff . h2[b] + cst ----
    if (wv == 1) {
        float acc = 0.0f;
#pragma unroll
        for (int s = 0; s < 2; ++s)
#pragma unroll
            for (int r = 0; r < 4; ++r) {
                const int u = 8 * q + 4 * s + r;
                float we = 0.0f;
                for (int j = 0; j < 32; ++j)
                    we += Wfc[j] * Wfc2[j * 32 + u];
                acc += we * hst[s][r];
            }
        acc += __shfl_xor(acc, 16);
        acc += __shfl_xor(acc, 32);
        if (q == 0) {
            float cst = bfc[0];
            for (int j = 0; j < 32; ++j) cst += Wfc[j] * bfc2[j];
            out[b0 + c] = acc + cst;
        }
    }
}

extern "C" void kernel_launch(void* const* d_in, const int* in_sizes, int n_in,
                              void* d_out, int out_size, void* d_ws, size_t ws_size,
                              hipStream_t stream) {
    const float* x    = (const float*)d_in[0];
    const float* Wih0 = (const float*)d_in[1];
    const float* Whh0 = (const float*)d_in[2];
    const float* bih0 = (const float*)d_in[3];
    const float* bhh0 = (const float*)d_in[4];
    const float* Wih1 = (const float*)d_in[5];
    const float* Whh1 = (const float*)d_in[6];
    const float* bih1 = (const float*)d_in[7];
    const float* bhh1 = (const float*)d_in[8];
    const float* Wfc2 = (const float*)d_in[9];
    const float* bfc2 = (const float*)d_in[10];
    const float* Wfc  = (const float*)d_in[11];
    const float* bfc  = (const float*)d_in[12];

    const int nblocks = out_size / 16;  // 4096/16 = 256
    hipLaunchKernelGGL(gru_fused, dim3(nblocks), dim3(128), 0, stream,
                       x, Wih0, Whh0, bih0, bhh0, Wih1, Whh1, bih1, bhh1,
                       Wfc2, bfc2, Wfc, bfc, (float*)d_out);
}

// Round 5
// 287.188 us; speedup vs baseline: 2.0038x; 2.0038x over previous
//
#include <hip/hip_runtime.h>

// 2-layer GRU (B=4096, S=512, IN=4, H=32) + FC(32->32) + FC(32->1), fp32 in/out.
// 4 waves/block: (layer L, unit-half hf). Layer pipeline with 1-step lag.
// 2-term MFMA: weights split hi+lo bf16 (exact to 2^-17), state quantized to
// bf16 hi only -> 12 MFMA/wave max, hi-only LDS exchange, chained accumulate.
// L0's published state fragment doubles as L1's input (shared buffer).
// x bulk-staged 16 steps ahead in an LDS ring. One barrier per step.

#define SEQ 512
#define LOG2E 1.44269504088896340736f

typedef __attribute__((ext_vector_type(8))) short  short8;
typedef __attribute__((ext_vector_type(4))) float  f32x4;
typedef __attribute__((ext_vector_type(2))) unsigned uint2v;

static __device__ __forceinline__ unsigned short f2bf(float f) {
    unsigned u = __builtin_bit_cast(unsigned, f);
    return (unsigned short)((u + 0x7fffu + ((u >> 16) & 1u)) >> 16);
}
static __device__ __forceinline__ float bf2f(unsigned short b) {
    return __builtin_bit_cast(float, ((unsigned)b) << 16);
}
static __device__ __forceinline__ unsigned cvtpk(float a, float b) {
    unsigned r;
    asm("v_cvt_pk_bf16_f32 %0, %1, %2" : "=v"(r) : "v"(a), "v"(b));
    return r;
}
static __device__ __forceinline__ float sigm(float x) {
    return __builtin_amdgcn_rcpf(1.0f + __builtin_amdgcn_exp2f(-LOG2E * x));
}
static __device__ __forceinline__ float tanh_(float x) {
    return 1.0f - 2.0f * __builtin_amdgcn_rcpf(1.0f + __builtin_amdgcn_exp2f((2.0f * LOG2E) * x));
}

#define MFMA(A, B, C) __builtin_amdgcn_mfma_f32_16x16x32_bf16((A), (B), (C), 0, 0, 0)

// weights hi/lo x state-hi, chained: (Whi + Wlo) * B + bias
static __device__ __forceinline__ f32x4 side2(short8 Wh, short8 Wl, short8 B,
                                              f32x4 bias) {
    f32x4 a = MFMA(Wh, B, bias);
    a = MFMA(Wl, B, a);
    return a;
}

static __device__ __forceinline__ void cvt8(const float* p, short8& h8, short8& l8) {
    f32x4 v0 = *(const f32x4*)p;
    f32x4 v1 = *(const f32x4*)(p + 4);
#pragma unroll
    for (int e = 0; e < 8; ++e) {
        float v = (e < 4) ? v0[e] : v1[e - 4];
        unsigned short hb = f2bf(v);
        h8[e] = (short)hb;
        l8[e] = (short)f2bf(v - bf2f(hb));
    }
}

__global__ __launch_bounds__(256, 1) void gru_fused(
    const float* __restrict__ x,
    const float* __restrict__ Wih0, const float* __restrict__ Whh0,
    const float* __restrict__ bih0, const float* __restrict__ bhh0,
    const float* __restrict__ Wih1, const float* __restrict__ Whh1,
    const float* __restrict__ bih1, const float* __restrict__ bhh1,
    const float* __restrict__ Wfc2, const float* __restrict__ bfc2,
    const float* __restrict__ Wfc,  const float* __restrict__ bfc,
    float* __restrict__ out)
{
    const int tid  = threadIdx.x;
    const int lane = tid & 63;
    const int wid  = tid >> 6;      // 0..3
    const int L    = wid >> 1;      // layer
    const int hf   = wid & 1;       // unit half: units [16*hf, 16*hf+16)
    const int c    = lane & 15;     // batch col
    const int q    = lane >> 4;     // 0..3
    const int b0   = blockIdx.x * 16;

    // LDS: ST01 = h1 frags (L0 state AND L1 input), 2 bufs x [16 rows][80B]
    //      ST2  = h2 frags (L1 state), 2 bufs x [16][80B]
    //      XS   = x ring, 32 steps x 16 rows x 16B
    //      EP   = epilogue scratch
    __shared__ __align__(16) char smem[2560 + 2560 + 8192 + 128];
    char*  ST01 = smem;
    char*  ST2  = smem + 2560;
    f32x4* XS   = (f32x4*)(smem + 5120);
    float* EP   = (float*)(smem + 13312);

    // zero both state-buffer regions (h = 0)
    for (int i = tid; i < 1280; i += 256) ((unsigned*)smem)[i] = 0u;

    // ------------- per-wave weight fragments (loop-invariant) -------------
    const float* Whp = L ? Whh1 : Whh0;
    const float* bhp = L ? bhh1 : bhh0;
    const int tts[3] = {hf, 2 + hf, 4 + hf};   // r,z,n tiles for this half

    short8 whhh[3], whhl[3], wuh[3], wul[3];
    f32x4  bxv[3], bhv[3];
    f32x4  wx0[12];      // L0 only: Wih0 rows (fp32 exact)
    float  bx0s[12];     // L0 only: bih0

#pragma unroll
    for (int j = 0; j < 3; ++j) {
        const int t = tts[j];
        cvt8(Whp + (16 * t + c) * 32 + 8 * q, whhh[j], whhl[j]);
        bhv[j] = *(const f32x4*)(bhp + 16 * t + 4 * q);
    }
    if (L == 0) {
#pragma unroll
        for (int j = 0; j < 3; ++j)
#pragma unroll
            for (int r = 0; r < 4; ++r) {
                const int g = 16 * tts[j] + 4 * q + r;
                wx0[4 * j + r]  = *(const f32x4*)(Wih0 + g * 4);
                bx0s[4 * j + r] = bih0[g];
            }
    } else {
#pragma unroll
        for (int j = 0; j < 3; ++j) {
            const int t = tts[j];
            cvt8(Wih1 + (16 * t + c) * 32 + 8 * q, wuh[j], wul[j]);
            bxv[j] = *(const f32x4*)(bih1 + 16 * t + 4 * q);
        }
    }

    // ------------- prologue: stage x steps 0..31 -------------
    {
        const int row = tid & 15;
        const int so  = tid >> 4;   // 0..15
#pragma unroll
        for (int k = 0; k < 2; ++k) {
            const int step = 16 * k + so;
            XS[step * 16 + row] =
                *(const f32x4*)(x + ((long)(b0 + row) * SEQ + step) * 4);
        }
    }

    float hst[4] = {0, 0, 0, 0};   // this wave's units 16hf+4q+r, batch c
    const int frag_off = c * 80 + q * 16;                 // b128 B-frag read
    const int wr_off   = c * 80 + (16 * hf + 4 * q) * 2;  // b64 D write (hi)

    __syncthreads();

    // ---------------- pipelined main loop: 513 iterations ----------------
    // iter i: L0 waves do step i (i<SEQ), L1 waves do step i-1 (i>=1).
    // L0: state read ST01[(i+1)&1], write ST01[i&1].
    // L1: input read ST01[(i+1)&1], state read ST2[i&1], write ST2[(i+1)&1].
#pragma unroll 2
    for (int i = 0; i <= SEQ; ++i) {
        // ---- bulk x staging: 16 steps, 16 iterations ahead ----
        if ((i & 15) == 0) {
            const int base = i + 16;
            if (base < SEQ) {
                const int row  = tid & 15;
                const int step = base + (tid >> 4);
                XS[(step & 31) * 16 + row] =
                    *(const f32x4*)(x + ((long)(b0 + row) * SEQ + step) * 4);
            }
        }

        const bool act = (L == 0) ? (i < SEQ) : (i >= 1);
        if (act) {
            f32x4 ax[3], ah[3];
            if (L == 0) {
                // issue state read first, cover latency with exact x-side FMAs
                const char* st = ST01 + ((i + 1) & 1) * 1280;
                short8 sfrag = *(const short8*)(st + frag_off);
                f32x4 xv = XS[(i & 31) * 16 + c];
#pragma unroll
                for (int j = 0; j < 3; ++j)
#pragma unroll
                    for (int r = 0; r < 4; ++r) {
                        f32x4 w = wx0[4 * j + r];
                        ax[j][r] = bx0s[4 * j + r] + w[0] * xv[0] + w[1] * xv[1]
                                 + w[2] * xv[2] + w[3] * xv[3];
                    }
#pragma unroll
                for (int j = 0; j < 3; ++j)
                    ah[j] = side2(whhh[j], whhl[j], sfrag, bhv[j]);
            } else {
                const char* us = ST01 + ((i + 1) & 1) * 1280;   // h1[i-1]
                short8 ufrag = *(const short8*)(us + frag_off);
                const char* st = ST2 + (i & 1) * 1280;          // h2[i-2]
                short8 sfrag = *(const short8*)(st + frag_off);
#pragma unroll
                for (int j = 0; j < 3; ++j)
                    ax[j] = side2(wuh[j], wul[j], ufrag, bxv[j]);
#pragma unroll
                for (int j = 0; j < 3; ++j)
                    ah[j] = side2(whhh[j], whhl[j], sfrag, bhv[j]);
            }

            float hv[4];
#pragma unroll
            for (int r = 0; r < 4; ++r) {
                float rg = sigm(ax[0][r] + ah[0][r]);
                float zg = sigm(ax[1][r] + ah[1][r]);
                float ng = tanh_(ax[2][r] + rg * ah[2][r]);
                float hN = ng + zg * (hst[r] - ng);
                hst[r] = hN;
                hv[r] = hN;
            }
            // hi-only pack: 2 cvtpk + single b64 store
            unsigned w0 = cvtpk(hv[0], hv[1]);
            unsigned w1 = cvtpk(hv[2], hv[3]);
            uint2v wh8 = {w0, w1};
            char* dst = (L == 0) ? (ST01 + (i & 1) * 1280)
                                 : (ST2 + ((i + 1) & 1) * 1280);
            *(uint2v*)(dst + wr_off) = wh8;
        }
        __syncthreads();
    }

    // ---------------- epilogue: out = Weff . h2 + cst ----------------
    if (L == 1) {
        float we[4] = {0, 0, 0, 0};
        const float* w2p = Wfc2 + 16 * hf + 4 * q;
#pragma unroll 8
        for (int j = 0; j < 32; ++j) {
            float wf = Wfc[j];
            f32x4 w2 = *(const f32x4*)(w2p + j * 32);
#pragma unroll
            for (int r = 0; r < 4; ++r) we[r] += wf * w2[r];
        }
        float acc = we[0] * hst[0] + we[1] * hst[1] + we[2] * hst[2] + we[3] * hst[3];
        acc += __shfl_xor(acc, 16);
        acc += __shfl_xor(acc, 32);
        if (q == 0) EP[hf * 16 + c] = acc;
    }
    __syncthreads();
    if (wid == 0 && q == 0) {
        float cst = bfc[0];
        for (int j = 0; j < 32; ++j) cst += Wfc[j] * bfc2[j];
        out[b0 + c] = EP[c] + EP[16 + c] + cst;
    }
}

extern "C" void kernel_launch(void* const* d_in, const int* in_sizes, int n_in,
                              void* d_out, int out_size, void* d_ws, size_t ws_size,
                              hipStream_t stream) {
    const float* x    = (const float*)d_in[0];
    const float* Wih0 = (const float*)d_in[1];
    const float* Whh0 = (const float*)d_in[2];
    const float* bih0 = (const float*)d_in[3];
    const float* bhh0 = (const float*)d_in[4];
    const float* Wih1 = (const float*)d_in[5];
    const float* Whh1 = (const float*)d_in[6];
    const float* bih1 = (const float*)d_in[7];
    const float* bhh1 = (const float*)d_in[8];
    const float* Wfc2 = (const float*)d_in[9];
    const float* bfc2 = (const float*)d_in[10];
    const float* Wfc  = (const float*)d_in[11];
    const float* bfc  = (const float*)d_in[12];

    const int nblocks = out_size / 16;  // 4096/16 = 256
    hipLaunchKernelGGL(gru_fused, dim3(nblocks), dim3(256), 0, stream,
                       x, Wih0, Whh0, bih0, bhh0, Wih1, Whh1, bih1, bhh1,
                       Wfc2, bfc2, Wfc, bfc, (float*)d_out);
}

// Round 7
// 221.187 us; speedup vs baseline: 2.6017x; 1.2984x over previous
//
#include <hip/hip_runtime.h>

// 2-layer GRU (B=4096, S=512, IN=4, H=32) + FC(32->32) + FC(32->1), fp32 in/out.
// 8 waves/block = (role: main/helper) x (layer) x (unit-half hf); 256 blocks.
// Helpers compute the feed-forward input side ahead of time into LDS (AX):
//   L0 helper: exact fp32 x-matvec (+ x HBM staging); L1 helper: Wih1*h1 MFMAs.
// Mains run the pure recurrence: 6 MFMA (Whh hi/lo x state-bf16, C-in = AX)
// -> gates -> pack -> LDS publish. 2 waves/SIMD (main+helper paired).
// PIPELINE LAGS (fix of R6's off-by-one): L0 main does step i at iter i;
// L1 helper at iter i computes P[i] = Wih1*h1[i-1]; L1 main does step i-2 at
// iter i, consuming P[i-1] = Wih1*h1[i-2] (matching-step input). 514 iters.
// Numerics = R5 (weights hi/lo exact, state bf16-hi): absmax ~5e-4.

#define SEQ 512
#define LOG2E 1.44269504088896340736f

typedef __attribute__((ext_vector_type(8))) short  short8;
typedef __attribute__((ext_vector_type(4))) float  f32x4;
typedef __attribute__((ext_vector_type(2))) unsigned uint2v;

static __device__ __forceinline__ unsigned short f2bf(float f) {
    unsigned u = __builtin_bit_cast(unsigned, f);
    return (unsigned short)((u + 0x7fffu + ((u >> 16) & 1u)) >> 16);
}
static __device__ __forceinline__ float bf2f(unsigned short b) {
    return __builtin_bit_cast(float, ((unsigned)b) << 16);
}
static __device__ __forceinline__ unsigned cvtpk(float a, float b) {
    unsigned r;
    asm("v_cvt_pk_bf16_f32 %0, %1, %2" : "=v"(r) : "v"(a), "v"(b));
    return r;
}
static __device__ __forceinline__ float sigm(float x) {
    return __builtin_amdgcn_rcpf(1.0f + __builtin_amdgcn_exp2f(-LOG2E * x));
}
static __device__ __forceinline__ float tanh_(float x) {
    return 1.0f - 2.0f * __builtin_amdgcn_rcpf(1.0f + __builtin_amdgcn_exp2f((2.0f * LOG2E) * x));
}

#define MFMA(A, B, C) __builtin_amdgcn_mfma_f32_16x16x32_bf16((A), (B), (C), 0, 0, 0)

// (Whi + Wlo) * B + Cin, chained accumulate (2 MFMAs, depth 2)
static __device__ __forceinline__ f32x4 side2(short8 Wh, short8 Wl, short8 B,
                                              f32x4 Cin) {
    f32x4 a = MFMA(Wh, B, Cin);
    a = MFMA(Wl, B, a);
    return a;
}

static __device__ __forceinline__ void cvt8(const float* p, short8& h8, short8& l8) {
    f32x4 v0 = *(const f32x4*)p;
    f32x4 v1 = *(const f32x4*)(p + 4);
#pragma unroll
    for (int e = 0; e < 8; ++e) {
        float v = (e < 4) ? v0[e] : v1[e - 4];
        unsigned short hb = f2bf(v);
        h8[e] = (short)hb;
        l8[e] = (short)f2bf(v - bf2f(hb));
    }
}

__global__ __launch_bounds__(512, 1) void gru_fused(
    const float* __restrict__ x,
    const float* __restrict__ Wih0, const float* __restrict__ Whh0,
    const float* __restrict__ bih0, const float* __restrict__ bhh0,
    const float* __restrict__ Wih1, const float* __restrict__ Whh1,
    const float* __restrict__ bih1, const float* __restrict__ bhh1,
    const float* __restrict__ Wfc2, const float* __restrict__ bfc2,
    const float* __restrict__ Wfc,  const float* __restrict__ bfc,
    float* __restrict__ out)
{
    const int tid  = threadIdx.x;
    const int lane = tid & 63;
    const int wid  = tid >> 6;          // 0..7  (SIMD = wid & 3)
    const int role = wid >> 2;          // 0 = main, 1 = helper
    const int L    = (wid >> 1) & 1;    // layer
    const int hf   = wid & 1;           // unit half
    const int c    = lane & 15;         // batch col
    const int q    = lane >> 4;         // 0..3
    const int b0   = blockIdx.x * 16;

    // LDS map:
    //  ST01: h1 frags (L0 state AND L1-helper input), 2 bufs x [16][80B] = 2560
    //  ST2 : h2 frags, 2 bufs x [16][80B]                                = 2560
    //  XS  : x ring, 32 steps x 16 rows x 16B                            = 8192
    //  AX0 : L0 preact, 2 bufs x 6 tiles x 4 q x 16 c x f32x4            = 12288
    //  AX1 : L1 preact, same                                             = 12288
    //  EP  : epilogue scratch                                            = 128
    __shared__ __align__(16) char smem[38016];
    char*  ST01 = smem;
    char*  ST2  = smem + 2560;
    f32x4* XS   = (f32x4*)(smem + 5120);
    f32x4* AX0  = (f32x4*)(smem + 13312);
    f32x4* AX1  = (f32x4*)(smem + 25600);
    float* EP   = (float*)(smem + 37888);

    // zero state buffers (h = 0)
    for (int i = tid; i < 1280; i += 512) ((unsigned*)smem)[i] = 0u;

    // stage x steps 0..31
    if (tid < 256) {
        const int row = tid & 15, so = tid >> 4;
#pragma unroll
        for (int k = 0; k < 2; ++k) {
            const int step = so + 16 * k;
            XS[step * 16 + row] =
                *(const f32x4*)(x + ((long)(b0 + row) * SEQ + step) * 4);
        }
    }

    const int tts[3] = {hf, 2 + hf, 4 + hf};   // r,z,n tiles for this half

    // ------------- per-role weight setup (wave-uniform branches) -----------
    short8 whhh[3], whhl[3];            // mains: Whh hi/lo
    f32x4  bhv2 = {0, 0, 0, 0};        // mains: bhh n-slice (C-in for j=2)
    f32x4  wx0[12];                     // L0 helper: Wih0 rows fp32
    float  bxs[12];                     // L0 helper: folded biases
    short8 wuh[3], wul[3];              // L1 helper: Wih1 hi/lo
    f32x4  bxv[3];                      // L1 helper: folded biases

    if (role == 0) {
        const float* Whp = L ? Whh1 : Whh0;
        const float* bhp = L ? bhh1 : bhh0;
#pragma unroll
        for (int j = 0; j < 3; ++j)
            cvt8(Whp + (16 * tts[j] + c) * 32 + 8 * q, whhh[j], whhl[j]);
        bhv2 = *(const f32x4*)(bhp + 16 * tts[2] + 4 * q);
    } else if (L == 0) {
#pragma unroll
        for (int j = 0; j < 3; ++j)
#pragma unroll
            for (int r = 0; r < 4; ++r) {
                const int g = 16 * tts[j] + 4 * q + r;
                wx0[4 * j + r] = *(const f32x4*)(Wih0 + g * 4);
                bxs[4 * j + r] = bih0[g] + ((j < 2) ? bhh0[g] : 0.0f);
            }
    } else {
#pragma unroll
        for (int j = 0; j < 3; ++j) {
            cvt8(Wih1 + (16 * tts[j] + c) * 32 + 8 * q, wuh[j], wul[j]);
            f32x4 bb = *(const f32x4*)(bih1 + 16 * tts[j] + 4 * q);
            if (j < 2) bb += *(const f32x4*)(bhh1 + 16 * tts[j] + 4 * q);
            bxv[j] = bb;
        }
    }

    // prologue: L0 helper fills AX0 buf0 with step 0 (direct global x read)
    if (role == 1 && L == 0) {
        f32x4 xv = *(const f32x4*)(x + (long)(b0 + c) * (SEQ * 4));
#pragma unroll
        for (int j = 0; j < 3; ++j) {
            f32x4 a;
#pragma unroll
            for (int r = 0; r < 4; ++r) {
                f32x4 w = wx0[4 * j + r];
                a[r] = bxs[4 * j + r] + w[0] * xv[0] + w[1] * xv[1]
                     + w[2] * xv[2] + w[3] * xv[3];
            }
            AX0[tts[j] * 64 + q * 16 + c] = a;
        }
    }

    float hst[4] = {0, 0, 0, 0};   // mains: units 16hf+4q+r, batch c
    const int frag_off = c * 80 + q * 16;                 // b128 B-frag read
    const int wr_off   = c * 80 + (16 * hf + 4 * q) * 2;  // b64 D write (hi)

    __syncthreads();

    // ---------------- pipelined main loop: 514 iterations ----------------
    // iter i: L0 main: step i (i<SEQ); reads AX0[i&1] (=P0[i], made at i-1),
    //                  state ST01[(i+1)&1], writes h1[i] -> ST01[i&1].
    //         L0 helper: AX0 for step i+1 -> AX0[(i+1)&1]; x staging.
    //         L1 helper: P[i] = Wih1*h1[i-1] (ST01[(i+1)&1]) -> AX1[i&1].
    //         L1 main: step i-2 (i>=2); reads AX1[(i+1)&1] (=P[i-1] =
    //                  Wih1*h1[i-2], matching step), state h2[i-3] from
    //                  ST2[(i+1)&1], writes h2[i-2] -> ST2[i&1].
#pragma unroll 2
    for (int i = 0; i <= SEQ + 1; ++i) {
        if (role == 0) {
            const bool act = (L == 0) ? (i < SEQ) : (i >= 2);
            if (act) {
                const char*  st;
                const f32x4* axb;
                char*        dst;
                if (L == 0) {
                    st  = ST01 + ((i + 1) & 1) * 1280;
                    axb = AX0 + (i & 1) * 384;
                    dst = ST01 + (i & 1) * 1280;
                } else {
                    st  = ST2 + ((i + 1) & 1) * 1280;
                    axb = AX1 + ((i + 1) & 1) * 384;
                    dst = ST2 + (i & 1) * 1280;
                }
                short8 sfrag = *(const short8*)(st + frag_off);
                f32x4 ax0v = axb[tts[0] * 64 + q * 16 + c];
                f32x4 ax1v = axb[tts[1] * 64 + q * 16 + c];
                f32x4 ax2v = axb[tts[2] * 64 + q * 16 + c];

                f32x4 p0 = side2(whhh[0], whhl[0], sfrag, ax0v);
                f32x4 p1 = side2(whhh[1], whhl[1], sfrag, ax1v);
                f32x4 p2 = side2(whhh[2], whhl[2], sfrag, bhv2);

                float hv[4];
#pragma unroll
                for (int r = 0; r < 4; ++r) {
                    float rg = sigm(p0[r]);
                    float zg = sigm(p1[r]);
                    float ng = tanh_(ax2v[r] + rg * p2[r]);
                    float hN = ng + zg * (hst[r] - ng);
                    hst[r] = hN;
                    hv[r] = hN;
                }
                unsigned w0 = cvtpk(hv[0], hv[1]);
                unsigned w1 = cvtpk(hv[2], hv[3]);
                uint2v wpk = {w0, w1};
                *(uint2v*)(dst + wr_off) = wpk;
            }
        } else if (L == 0) {
            // ---- x HBM staging: 16 steps, 16 iterations ahead ----
            if ((i & 15) == 0) {
                const int base = i + 16;
                if (base < SEQ) {
                    const int hidx = tid - 256;          // 0..127
                    const int row = hidx & 15, so = hidx >> 4;
#pragma unroll
                    for (int k = 0; k < 2; ++k) {
                        const int step = base + so + 8 * k;
                        XS[(step & 31) * 16 + row] =
                            *(const f32x4*)(x + ((long)(b0 + row) * SEQ + step) * 4);
                    }
                }
            }
            // ---- AX0 for step i+1 (exact fp32 x-matvec) ----
            const int step = i + 1;
            if (step < SEQ) {
                f32x4 xv = XS[(step & 31) * 16 + c];
                f32x4* dstax = AX0 + (step & 1) * 384;
#pragma unroll
                for (int j = 0; j < 3; ++j) {
                    f32x4 a;
#pragma unroll
                    for (int r = 0; r < 4; ++r) {
                        f32x4 w = wx0[4 * j + r];
                        a[r] = bxs[4 * j + r] + w[0] * xv[0] + w[1] * xv[1]
                             + w[2] * xv[2] + w[3] * xv[3];
                    }
                    dstax[tts[j] * 64 + q * 16 + c] = a;
                }
            }
        } else {
            // ---- L1 helper: P[i] = Wih1 * h1[i-1] + biases -> AX1[i&1] ----
            if (i <= SEQ) {
                const char* us = ST01 + ((i + 1) & 1) * 1280;   // h1[i-1]
                short8 uf = *(const short8*)(us + frag_off);
                f32x4* dstax = AX1 + (i & 1) * 384;
#pragma unroll
                for (int j = 0; j < 3; ++j) {
                    f32x4 a = side2(wuh[j], wul[j], uf, bxv[j]);
                    dstax[tts[j] * 64 + q * 16 + c] = a;
                }
            }
        }
        __syncthreads();
    }

    // ---------------- epilogue: out = Weff . h2 + cst ----------------
    if (role == 0 && L == 1) {
        float we[4] = {0, 0, 0, 0};
        const float* w2p = Wfc2 + 16 * hf + 4 * q;
#pragma unroll 8
        for (int j = 0; j < 32; ++j) {
            float wf = Wfc[j];
            f32x4 w2 = *(const f32x4*)(w2p + j * 32);
#pragma unroll
            for (int r = 0; r < 4; ++r) we[r] += wf * w2[r];
        }
        float acc = we[0] * hst[0] + we[1] * hst[1] + we[2] * hst[2] + we[3] * hst[3];
        acc += __shfl_xor(acc, 16);
        acc += __shfl_xor(acc, 32);
        if (q == 0) EP[hf * 16 + c] = acc;
    }
    __syncthreads();
    if (wid == 0 && q == 0) {
        float cst = bfc[0];
        for (int j = 0; j < 32; ++j) cst += Wfc[j] * bfc2[j];
        out[b0 + c] = EP[c] + EP[16 + c] + cst;
    }
}

extern "C" void kernel_launch(void* const* d_in, const int* in_sizes, int n_in,
                              void* d_out, int out_size, void* d_ws, size_t ws_size,
                              hipStream_t stream) {
    const float* x    = (const float*)d_in[0];
    const float* Wih0 = (const float*)d_in[1];
    const float* Whh0 = (const float*)d_in[2];
    const float* bih0 = (const float*)d_in[3];
    const float* bhh0 = (const float*)d_in[4];
    const float* Wih1 = (const float*)d_in[5];
    const float* Whh1 = (const float*)d_in[6];
    const float* bih1 = (const float*)d_in[7];
    const float* bhh1 = (const float*)d_in[8];
    const float* Wfc2 = (const float*)d_in[9];
    const float* bfc2 = (const float*)d_in[10];
    const float* Wfc  = (const float*)d_in[11];
    const float* bfc  = (const float*)d_in[12];

    const int nblocks = out_size / 16;  // 4096/16 = 256
    hipLaunchKernelGGL(gru_fused, dim3(nblocks), dim3(512), 0, stream,
                       x, Wih0, Whh0, bih0, bhh0, Wih1, Whh1, bih1, bhh1,
                       Wfc2, bfc2, Wfc, bfc, (float*)d_out);
}